// Round 8
// baseline (207.066 us; speedup 1.0000x reference)
//
#include <hip/hip_runtime.h>
#include <hip/hip_bf16.h>
#include <hip/hip_fp16.h>
#include <cstddef>

// Problem constants
#define NB 2
#define QN 12240
#define SN 12240
#define MREAL 24480          // NB*QN rows (= 1530 panels of 16)
#define MPAD  24576

typedef unsigned short ushortT;
typedef unsigned int uintT;
typedef __bf16 bf16x8 __attribute__((ext_vector_type(8)));
typedef float f32x4 __attribute__((ext_vector_type(4)));

__device__ __forceinline__ ushortT f2bf(float f) {
    uintT u = __float_as_uint(f);
    uintT r = u + 0x7fffu + ((u >> 16) & 1u);   // RNE
    return (ushortT)(r >> 16);
}
__device__ __forceinline__ float bf_lo(uintT u) { return __uint_as_float(u << 16); }
__device__ __forceinline__ float bf_hi(uintT u) { return __uint_as_float(u & 0xffff0000u); }

__device__ __forceinline__ void async_ld16(const ushortT* g, ushortT* l) {
    __builtin_amdgcn_global_load_lds(
        (const __attribute__((address_space(1))) unsigned int*)g,
        (__attribute__((address_space(3))) unsigned int*)l, 16, 0, 0);
}

// ---------------------------------------------------------------------------
// Merged cast kernel (unchanged from R7).
// ---------------------------------------------------------------------------
__global__ __launch_bounds__(256) void cast_all(
    const float* __restrict__ q, const float* __restrict__ src,
    const float* __restrict__ Wval, const float* __restrict__ Wattn,
    const float* __restrict__ Woff, const float* __restrict__ Wout,
    ushortT* __restrict__ qb, ushortT* __restrict__ sb,
    ushortT* __restrict__ tval, ushortT* __restrict__ tlo,
    ushortT* __restrict__ tout)
{
    int bx = blockIdx.x;
    if (bx < 6120) {
        const int issrc = bx >= 3060;
        const size_t idx = ((size_t)(bx - (issrc ? 3060 : 0)) * 256 + threadIdx.x) * 8;
        const float* in = issrc ? src : q;
        ushortT* out = issrc ? sb : qb;
        const float4 a = *(const float4*)(in + idx);
        const float4 b = *(const float4*)(in + idx + 4);
        uint4 o;
        o.x = (uintT)f2bf(a.x) | ((uintT)f2bf(a.y) << 16);
        o.y = (uintT)f2bf(a.z) | ((uintT)f2bf(a.w) << 16);
        o.z = (uintT)f2bf(b.x) | ((uintT)f2bf(b.y) << 16);
        o.w = (uintT)f2bf(b.z) | ((uintT)f2bf(b.w) << 16);
        *(uint4*)(out + idx) = o;
        return;
    }
    bx -= 6120;
    const float* W; ushortT* T; int n, Nw, trow;
    if (bx < 256)      { W = Wval;  T = tval; n = bx;       Nw = 256; trow = n; }
    else if (bx < 384) { W = Wattn; T = tlo;  n = bx - 256; Nw = 128; trow = n; }
    else if (bx < 640) { W = Woff;  T = tlo;  n = bx - 384; Nw = 256; trow = n + 128; }
    else               { W = Wout;  T = tout; n = bx - 640; Nw = 256; trow = n; }
    const int k = threadIdx.x;
    T[(size_t)trow * 256 + k] = f2bf(W[(size_t)k * Nw + n]);
}

// ---------------------------------------------------------------------------
// Skinny-K GEMM, B-in-registers / A-panel streaming.
// Block = 512 threads = 8 waves. Wave w owns a 32-col slab: its full-K B
// fragments (16 x bf16x8 = 64 VGPR) load once from L2. Blocks iterate 3
// panels of 16 A-rows; panel (8 KB) staged to LDS via global_load_lds with
// XOR-(r&7) chunk swizzle (conflict-free ds_read_b128), double-buffered:
// ONE barrier per panel, 16 MFMAs/wave/panel, zero B re-staging.
// bx==0: v = src@W_val -> head-major bf16. bx in {1,2}: lo = q@[Wattn;Woff]
// (N padded to 512 compute-side; stores guarded at 384).
// ---------------------------------------------------------------------------
__global__ __launch_bounds__(512, 4) void gemm_vlo(
    const ushortT* __restrict__ q_bf, const ushortT* __restrict__ src_bf,
    const ushortT* __restrict__ wt_val, const ushortT* __restrict__ wt_lo,
    const float* __restrict__ b_val, const float* __restrict__ b_attn,
    const float* __restrict__ b_off,
    ushortT* __restrict__ v_bf, float* __restrict__ lo_ws)
{
    const int bx = blockIdx.x;
    const int tid = threadIdx.x, wave = tid >> 6, lane = tid & 63;
    const bool isv = (bx == 0);
    const ushortT* A  = isv ? src_bf : q_bf;
    const ushortT* Bt = isv ? wt_val : wt_lo;
    const int colbase = (isv ? 0 : (bx - 1) * 256) + wave * 32;

    // B fragments for the whole K range (once)
    bf16x8 bfrag[8][2];
    {
        const int br = lane & 15, bk = (lane >> 4) * 8;
        #pragma unroll
        for (int k = 0; k < 8; k++)
            #pragma unroll
            for (int j = 0; j < 2; j++)
                bfrag[k][j] = *(const bf16x8*)(
                    Bt + (size_t)(colbase + j * 16 + br) * 256 + k * 32 + bk);
    }

    __shared__ __attribute__((aligned(16))) ushortT Apan[2][4096];  // 2 x 8 KB

    const int prow0 = blockIdx.y * 48;          // 3 panels x 16 rows
    const int sr = tid >> 5, sc = tid & 31;
    const int sgc = sc ^ (sr & 7);              // staging chunk swizzle

    async_ld16(A + (size_t)(prow0 + sr) * 256 + sgc * 8, &Apan[0][tid * 8]);

    const int rr = lane & 15, q4 = lane >> 4;

    #pragma unroll
    for (int i = 0; i < 3; i++) {
        __syncthreads();                        // staging of panel i complete
        if (i < 2)
            async_ld16(A + (size_t)(prow0 + (i + 1) * 16 + sr) * 256 + sgc * 8,
                       &Apan[(i + 1) & 1][tid * 8]);

        f32x4 acc0 = (f32x4)0.f, acc1 = (f32x4)0.f;
        const ushortT* Ap = &Apan[i & 1][0];
        #pragma unroll
        for (int k = 0; k < 8; k++) {
            const int p = (k * 4 + q4) ^ (rr & 7);
            const bf16x8 af = *(const bf16x8*)(Ap + rr * 256 + p * 8);
            acc0 = __builtin_amdgcn_mfma_f32_16x16x32_bf16(af, bfrag[k][0], acc0, 0, 0, 0);
            acc1 = __builtin_amdgcn_mfma_f32_16x16x32_bf16(af, bfrag[k][1], acc1, 0, 0, 0);
        }

        const int rowb = prow0 + i * 16 + q4 * 4;
        if (isv) {
            #pragma unroll
            for (int j = 0; j < 2; j++) {
                const int col = colbase + j * 16 + rr;
                const int head = col >> 5, ch = col & 31;
                const f32x4 a = j ? acc1 : acc0;
                const float bb = b_val[col];
                #pragma unroll
                for (int r = 0; r < 4; r++) {
                    const int row = rowb + r;
                    const int nn = (row >= SN) ? 1 : 0;
                    const int s = row - nn * SN;
                    v_bf[(((size_t)(nn * 8 + head)) * SN + s) * 32 + ch] = f2bf(a[r] + bb);
                }
            }
        } else {
            #pragma unroll
            for (int j = 0; j < 2; j++) {
                const int col = colbase + j * 16 + rr;
                if (col < 384) {
                    const float bb = (col < 128) ? b_attn[col] : b_off[col - 128];
                    const f32x4 a = j ? acc1 : acc0;
                    #pragma unroll
                    for (int r = 0; r < 4; r++)
                        lo_ws[(size_t)(rowb + r) * 384 + col] = a[r] + bb;
                }
            }
        }
    }
}

// ---------------------------------------------------------------------------
// Out GEMM, same structure: out = mdv(bf16) @ wt_out^T + b_out -> d_out fp32.
// ---------------------------------------------------------------------------
__global__ __launch_bounds__(512, 4) void gemm_out(
    const ushortT* __restrict__ A, const ushortT* __restrict__ Bt,
    const float* __restrict__ bias, float* __restrict__ C)
{
    const int tid = threadIdx.x, wave = tid >> 6, lane = tid & 63;
    const int colbase = wave * 32;

    bf16x8 bfrag[8][2];
    {
        const int br = lane & 15, bk = (lane >> 4) * 8;
        #pragma unroll
        for (int k = 0; k < 8; k++)
            #pragma unroll
            for (int j = 0; j < 2; j++)
                bfrag[k][j] = *(const bf16x8*)(
                    Bt + (size_t)(colbase + j * 16 + br) * 256 + k * 32 + bk);
    }

    __shared__ __attribute__((aligned(16))) ushortT Apan[2][4096];

    const int prow0 = blockIdx.y * 48;
    const int sr = tid >> 5, sc = tid & 31;
    const int sgc = sc ^ (sr & 7);

    async_ld16(A + (size_t)(prow0 + sr) * 256 + sgc * 8, &Apan[0][tid * 8]);

    const int rr = lane & 15, q4 = lane >> 4;

    #pragma unroll
    for (int i = 0; i < 3; i++) {
        __syncthreads();
        if (i < 2)
            async_ld16(A + (size_t)(prow0 + (i + 1) * 16 + sr) * 256 + sgc * 8,
                       &Apan[(i + 1) & 1][tid * 8]);

        f32x4 acc0 = (f32x4)0.f, acc1 = (f32x4)0.f;
        const ushortT* Ap = &Apan[i & 1][0];
        #pragma unroll
        for (int k = 0; k < 8; k++) {
            const int p = (k * 4 + q4) ^ (rr & 7);
            const bf16x8 af = *(const bf16x8*)(Ap + rr * 256 + p * 8);
            acc0 = __builtin_amdgcn_mfma_f32_16x16x32_bf16(af, bfrag[k][0], acc0, 0, 0, 0);
            acc1 = __builtin_amdgcn_mfma_f32_16x16x32_bf16(af, bfrag[k][1], acc1, 0, 0, 0);
        }

        const int rowb = prow0 + i * 16 + q4 * 4;
        #pragma unroll
        for (int j = 0; j < 2; j++) {
            const int col = colbase + j * 16 + rr;
            const float bb = bias[col];
            const f32x4 a = j ? acc1 : acc0;
            #pragma unroll
            for (int r = 0; r < 4; r++)
                C[(size_t)(rowb + r) * 256 + col] = a[r] + bb;
        }
    }
}

// ---------------------------------------------------------------------------
// Per-head two-phase sample kernel (unchanged from R7).
// ---------------------------------------------------------------------------
__global__ __launch_bounds__(128) void sample_kernel(
    const float* __restrict__ lo,       // (N*Q, 384): [0,128) logits, [128,384) off
    const float* __restrict__ geom,     // (N*Q, 4)
    const ushortT* __restrict__ v,      // (N, 8, S, 32) bf16 head-major
    ushortT* __restrict__ out)          // (N*Q, 256) bf16 mdv
{
    const int tid  = threadIdx.x;
    const int w    = tid >> 6;
    const int lane = tid & 63;
    const int qi   = lane >> 3;
    const int m    = blockIdx.y;
    const int n    = blockIdx.z;
    const int q    = blockIdx.x * 16 + w * 8 + qi;

    __shared__ __attribute__((aligned(16))) int pls[2][544];

    const size_t qb = (size_t)n * QN + q;

    // ---- phase 1 ----
    {
        const int p = lane & 7;
        const float* lorow = lo + qb * 384;
        const float2 lg = *(const float2*)(lorow + m * 16 + p * 2);
        const float4 of = *(const float4*)(lorow + 128 + m * 32 + p * 4);
        const float4 g  = *(const float4*)(geom + qb * 4);

        float mx = fmaxf(lg.x, lg.y);
        mx = fmaxf(mx, __shfl_xor(mx, 1));
        mx = fmaxf(mx, __shfl_xor(mx, 2));
        mx = fmaxf(mx, __shfl_xor(mx, 4));
        const float e0 = __expf(lg.x - mx);
        const float e1 = __expf(lg.y - mx);
        float s = e0 + e1;
        s += __shfl_xor(s, 1);
        s += __shfl_xor(s, 2);
        s += __shfl_xor(s, 4);
        const float inv = 1.f / s;

        const int l  = p >> 1;
        const int Wl = 96 >> l;
        const int s0 = (l == 0) ? 0 : (l == 1) ? 9216 : (l == 2) ? 11520 : 12096;
        const float cx = g.x, cy = g.y;
        const float sx = g.z * 0.125f, sy = g.w * 0.125f;
        int* myrec = &pls[w][qi * 68 + p * 8];

        #pragma unroll
        for (int t = 0; t < 2; t++) {
            const float ox = t ? of.z : of.x;
            const float oy = t ? of.w : of.y;
            const float wa = (t ? e1 : e0) * inv;

            const float x = (cx + ox * sx) * (float)Wl - 0.5f;
            const float y = (cy + oy * sy) * (float)Wl - 0.5f;
            const float xf = floorf(x), yf = floorf(y);
            const int x0 = (int)xf, y0 = (int)yf;
            const float wx = x - xf, wy = y - yf;

            const bool vx0 = (x0 >= 0) & (x0 < Wl);
            const bool vx1 = (x0 + 1 >= 0) & (x0 + 1 < Wl);
            const bool vy0 = (y0 >= 0) & (y0 < Wl);
            const bool vy1 = (y0 + 1 >= 0) & (y0 + 1 < Wl);

            const float w00 = (vx0 & vy0) ? wa * (1.f - wx) * (1.f - wy) : 0.f;
            const float w10 = (vx1 & vy0) ? wa * wx * (1.f - wy) : 0.f;
            const float w01 = (vx0 & vy1) ? wa * (1.f - wx) * wy : 0.f;
            const float w11 = (vx1 & vy1) ? wa * wx * wy : 0.f;

            const int xc0 = min(max(x0, 0), Wl - 1);
            const int xc1 = min(max(x0 + 1, 0), Wl - 1);
            const int yc0 = min(max(y0, 0), Wl - 1);
            const int yc1 = min(max(y0 + 1, 0), Wl - 1);

            const int iv0   = (s0 + yc0 * Wl + xc0) << 6;   // byte off, row 64B
            const int dx    = (xc1 - xc0) << 6;
            const int dyrow = ((yc1 - yc0) * Wl) << 6;
            __half2 h01 = __floats2half2_rn(w00, w10);
            __half2 h23 = __floats2half2_rn(w01, w11);
            int4 rec;
            rec.x = iv0;
            rec.y = dx | (dyrow << 16);
            rec.z = *reinterpret_cast<int*>(&h01);
            rec.w = *reinterpret_cast<int*>(&h23);
            *(int4*)(myrec + t * 4) = rec;
        }
    }
    __syncthreads();

    // ---- phase 2 ----
    const int c = lane & 7;
    const unsigned char* vb = (const unsigned char*)
        (v + ((size_t)(n * 8 + m) * SN) * 32) + c * 8;
    const int* grec = &pls[w][qi * 68];

    float a0 = 0.f, a1 = 0.f, a2 = 0.f, a3 = 0.f;

    #pragma unroll
    for (int lk = 0; lk < 16; lk++) {
        const int4 rec = *(const int4*)(grec + lk * 4);
        const int base = rec.x;
        const int dx   = rec.y & 0xffff;
        const int dy   = ((uintT)rec.y) >> 16;

        const uint2 u0 = *(const uint2*)(vb + base);
        const uint2 u1 = *(const uint2*)(vb + base + dx);
        const uint2 u2 = *(const uint2*)(vb + base + dy);
        const uint2 u3 = *(const uint2*)(vb + base + dy + dx);

        const __half2 h01 = *reinterpret_cast<const __half2*>(&rec.z);
        const __half2 h23 = *reinterpret_cast<const __half2*>(&rec.w);
        const float2 wlo = __half22float2(h01);
        const float2 whi = __half22float2(h23);

        a0 += wlo.x * bf_lo(u0.x) + wlo.y * bf_lo(u1.x) + whi.x * bf_lo(u2.x) + whi.y * bf_lo(u3.x);
        a1 += wlo.x * bf_hi(u0.x) + wlo.y * bf_hi(u1.x) + whi.x * bf_hi(u2.x) + whi.y * bf_hi(u3.x);
        a2 += wlo.x * bf_lo(u0.y) + wlo.y * bf_lo(u1.y) + whi.x * bf_lo(u2.y) + whi.y * bf_lo(u3.y);
        a3 += wlo.x * bf_hi(u0.y) + wlo.y * bf_hi(u1.y) + whi.x * bf_hi(u2.y) + whi.y * bf_hi(u3.y);
    }

    ushort4 o;
    o.x = f2bf(a0); o.y = f2bf(a1); o.z = f2bf(a2); o.w = f2bf(a3);
    *(ushort4*)(out + qb * 256 + m * 32 + c * 4) = o;
}

// ---------------------------------------------------------------------------
extern "C" void kernel_launch(void* const* d_in, const int* in_sizes, int n_in,
                              void* d_out, int out_size, void* d_ws, size_t ws_size,
                              hipStream_t stream)
{
    const float* queries = (const float*)d_in[0];
    const float* geom    = (const float*)d_in[1];
    const float* src     = (const float*)d_in[2];
    const float* W_off   = (const float*)d_in[3];
    const float* b_off   = (const float*)d_in[4];
    const float* W_attn  = (const float*)d_in[5];
    const float* b_attn  = (const float*)d_in[6];
    const float* W_val   = (const float*)d_in[7];
    const float* b_val   = (const float*)d_in[8];
    const float* W_out   = (const float*)d_in[9];
    const float* b_out   = (const float*)d_in[10];
    float* out = (float*)d_out;

    ushortT* wsb = (ushortT*)d_ws;
    const size_t PADROW = (size_t)MPAD * 256;          // 6,291,456 elems
    ushortT* q_bf    = wsb;
    ushortT* srcmdv  = wsb + PADROW;                   // src_bf, later mdv_bf
    ushortT* v_bf    = wsb + 2 * PADROW;               // head-major v
    ushortT* wt_val  = wsb + 3 * PADROW;               // 256*256
    ushortT* wt_lo   = wt_val + 65536;                 // 512*256 (384 real + pad)
    ushortT* wt_out  = wt_lo + 131072;                 // 256*256
    float* lo_ws = (float*)(wt_out + 65536);           // 24480*384 fp32
    // total ~76 MB

    cast_all<<<dim3(7016), dim3(256), 0, stream>>>(
        queries, src, W_val, W_attn, W_off, W_out,
        q_bf, srcmdv, wt_val, wt_lo, wt_out);

    // bx=0: v = src@W_val -> v_bf (head-major); bx=1,2: lo = q@[Wattn;Woff]
    gemm_vlo<<<dim3(3, 510), dim3(512), 0, stream>>>(
        q_bf, srcmdv, wt_val, wt_lo, b_val, b_attn, b_off, v_bf, lo_ws);

    sample_kernel<<<dim3(QN / 16, 8, NB), dim3(128), 0, stream>>>(
        lo_ws, geom, v_bf, srcmdv);

    gemm_out<<<dim3(1, 510), dim3(512), 0, stream>>>(srcmdv, wt_out, b_out, out);
}